// Round 1
// baseline (114.065 us; speedup 1.0000x reference)
//
#include <hip/hip_runtime.h>
#include <stdint.h>

#define B_  32
#define C_  256
#define HW_ 4096
#define K_  1024

__device__ __forceinline__ uint32_t f2key(float f) {
    uint32_t b = __float_as_uint(f);
    // order-preserving map: key ascending <=> float ascending
    return b ^ ((b & 0x80000000u) ? 0xFFFFFFFFu : 0x80000000u);
}

// Kernel A: per-pixel channel sums. 512 blocks x 256 threads.
__global__ void ps_sum_kernel(const float* __restrict__ f, float* __restrict__ sums) {
    int b = blockIdx.x >> 4;                       // 16 blocks per batch
    int p = ((blockIdx.x & 15) << 8) | threadIdx.x;
    const float* base = f + (size_t)b * C_ * HW_ + p;
    float s0 = 0.f, s1 = 0.f, s2 = 0.f, s3 = 0.f;
    #pragma unroll 4
    for (int c = 0; c < C_; c += 4) {
        s0 += base[(size_t)(c + 0) * HW_];
        s1 += base[(size_t)(c + 1) * HW_];
        s2 += base[(size_t)(c + 2) * HW_];
        s3 += base[(size_t)(c + 3) * HW_];
    }
    sums[(size_t)b * HW_ + p] = (s0 + s1) + (s2 + s3);
}

// Kernel B: per-batch exact top-K threshold (radix select) + tie-aware mask.
// 32 blocks x 1024 threads. Replicates jax.lax.top_k tie-break (lower index first).
__global__ void __launch_bounds__(1024) ps_select_kernel(const float* __restrict__ sums,
                                                         float* __restrict__ mask) {
    __shared__ uint32_t keys[HW_];
    __shared__ uint32_t bins[256];
    __shared__ uint32_t scanbuf[1024];
    __shared__ uint32_t sh_bcast[2];

    const int b = blockIdx.x;
    const int t = threadIdx.x;
    const float* row = sums + (size_t)b * HW_;

    #pragma unroll
    for (int j = 0; j < 4; ++j) {
        int p = j * 1024 + t;                      // coalesced load
        keys[p] = f2key(row[p]);
    }
    __syncthreads();

    uint32_t prefix = 0;
    uint32_t krem   = K_;
    for (int shift = 24; shift >= 0; shift -= 8) {
        if (t < 256) bins[t] = 0;
        __syncthreads();
        uint32_t abovemask = (shift == 24) ? 0u : (0xFFFFFFFFu << (shift + 8));
        #pragma unroll
        for (int j = 0; j < 4; ++j) {
            uint32_t key = keys[t * 4 + j];
            if ((key & abovemask) == prefix)
                atomicAdd(&bins[(key >> shift) & 255], 1u);
        }
        __syncthreads();
        if (t == 0) {
            uint32_t cum = 0; int chosen = 0;
            for (int i = 255; i >= 0; --i) {
                if (cum + bins[i] >= krem) { chosen = i; break; }
                cum += bins[i];
            }
            sh_bcast[0] = prefix | ((uint32_t)chosen << shift);
            sh_bcast[1] = krem - cum;
        }
        __syncthreads();
        prefix = sh_bcast[0];
        krem   = sh_bcast[1];
        __syncthreads();
    }

    const uint32_t T    = prefix;  // k-th largest key
    const uint32_t need = krem;    // how many ties (==T) to include, lowest index first

    // equality flags + block-wide exclusive scan (Hillis-Steele over 1024 threads)
    uint32_t e[4];
    uint32_t c = 0;
    #pragma unroll
    for (int j = 0; j < 4; ++j) {
        uint32_t key = keys[t * 4 + j];
        e[j] = (key == T) ? 1u : 0u;
        c += e[j];
    }
    scanbuf[t] = c;
    __syncthreads();
    for (int off = 1; off < 1024; off <<= 1) {
        uint32_t v = (t >= off) ? scanbuf[t - off] : 0u;
        __syncthreads();
        scanbuf[t] += v;
        __syncthreads();
    }
    uint32_t run = scanbuf[t] - c;                 // exclusive prefix of ties before my pixels

    float* mrow = mask + (size_t)b * HW_;
    #pragma unroll
    for (int j = 0; j < 4; ++j) {
        uint32_t key = keys[t * 4 + j];
        bool drop = (key > T) || (e[j] && (run < need));
        run += e[j];
        mrow[t * 4 + j] = drop ? 0.0f : 1.0f;
    }
}

// Kernel C: out = f * mask (broadcast over channels), float4-vectorized.
__global__ void ps_apply_kernel(const float4* __restrict__ f4,
                                const float4* __restrict__ mask4,
                                float4* __restrict__ out4) {
    size_t i = (size_t)blockIdx.x * blockDim.x + threadIdx.x;  // over 8388608 float4s
    float4 v = f4[i];
    size_t b  = i >> 18;           // (C_*HW_/4) = 262144 float4 per batch
    size_t p4 = i & 1023;          // HW_/4 - 1
    float4 m = mask4[(b << 10) + p4];
    v.x *= m.x; v.y *= m.y; v.z *= m.z; v.w *= m.w;
    out4[i] = v;
}

extern "C" void kernel_launch(void* const* d_in, const int* in_sizes, int n_in,
                              void* d_out, int out_size, void* d_ws, size_t ws_size,
                              hipStream_t stream) {
    const float* f = (const float*)d_in[0];
    float* out = (float*)d_out;

    float* sums = (float*)d_ws;                        // 32*4096 floats = 512 KiB
    float* mask = sums + (size_t)B_ * HW_;             // 32*4096 floats = 512 KiB

    ps_sum_kernel<<<dim3(B_ * (HW_ / 256)), dim3(256), 0, stream>>>(f, sums);
    ps_select_kernel<<<dim3(B_), dim3(1024), 0, stream>>>(sums, mask);

    size_t total4 = (size_t)B_ * C_ * HW_ / 4;         // 8388608
    ps_apply_kernel<<<dim3((unsigned)(total4 / 256)), dim3(256), 0, stream>>>(
        (const float4*)f, (const float4*)mask, (float4*)out);
}

// Round 2
// 76.169 us; speedup vs baseline: 1.4975x; 1.4975x over previous
//
#include <hip/hip_runtime.h>
#include <stdint.h>

#define B_  32
#define C_  256
#define HW_ 4096
#define K_  1024

__device__ __forceinline__ uint32_t f2key(float f) {
    uint32_t b = __float_as_uint(f);
    return b ^ ((b & 0x80000000u) ? 0xFFFFFFFFu : 0x80000000u);
}

// Kernel A: per-pixel channel sums, float4 over pixels.
// 512 blocks x 64 threads; each thread owns 4 consecutive pixels.
// Per-pixel arithmetic order identical to round 0 (4 interleaved chains).
__global__ void ps_sum_kernel(const float4* __restrict__ f4, float4* __restrict__ sums4) {
    int gid = blockIdx.x * 64 + threadIdx.x;       // 0..32767
    int b   = gid >> 10;                           // 1024 float4-pixels per batch
    int p4  = gid & 1023;
    const float4* base = f4 + (size_t)b * C_ * (HW_ / 4) + p4;
    float4 s0 = {0,0,0,0}, s1 = {0,0,0,0}, s2 = {0,0,0,0}, s3 = {0,0,0,0};
    #pragma unroll 4
    for (int c = 0; c < C_; c += 4) {
        float4 v0 = base[(size_t)(c + 0) * (HW_ / 4)];
        float4 v1 = base[(size_t)(c + 1) * (HW_ / 4)];
        float4 v2 = base[(size_t)(c + 2) * (HW_ / 4)];
        float4 v3 = base[(size_t)(c + 3) * (HW_ / 4)];
        s0.x += v0.x; s0.y += v0.y; s0.z += v0.z; s0.w += v0.w;
        s1.x += v1.x; s1.y += v1.y; s1.z += v1.z; s1.w += v1.w;
        s2.x += v2.x; s2.y += v2.y; s2.z += v2.z; s2.w += v2.w;
        s3.x += v3.x; s3.y += v3.y; s3.z += v3.z; s3.w += v3.w;
    }
    float4 r;
    r.x = (s0.x + s1.x) + (s2.x + s3.x);
    r.y = (s0.y + s1.y) + (s2.y + s3.y);
    r.z = (s0.z + s1.z) + (s2.z + s3.z);
    r.w = (s0.w + s1.w) + (s2.w + s3.w);
    sums4[(size_t)b * (HW_ / 4) + p4] = r;
}

// Kernel B: per-batch exact top-K threshold (radix select) + tie-aware mask.
// 32 blocks x 1024 threads. Each thread owns 4 keys in registers throughout.
__global__ void __launch_bounds__(1024) ps_select_kernel(const float* __restrict__ sums,
                                                         float* __restrict__ mask) {
    __shared__ uint32_t bins[256];
    __shared__ uint32_t wred[16];
    __shared__ uint32_t sh_bcast[2];

    const int b    = blockIdx.x;
    const int t    = threadIdx.x;
    const int lane = t & 63;
    const int wid  = t >> 6;

    float4 v = ((const float4*)(sums + (size_t)b * HW_))[t];
    uint32_t k0 = f2key(v.x), k1 = f2key(v.y), k2 = f2key(v.z), k3 = f2key(v.w);

    uint32_t prefix = 0;
    uint32_t krem   = K_;
    #pragma unroll
    for (int shift = 24; shift >= 0; shift -= 8) {
        if (t < 256) bins[t] = 0;
        __syncthreads();
        uint32_t abovemask = (shift == 24) ? 0u : (0xFFFFFFFFu << (shift + 8));
        if ((k0 & abovemask) == prefix) atomicAdd(&bins[(k0 >> shift) & 255], 1u);
        if ((k1 & abovemask) == prefix) atomicAdd(&bins[(k1 >> shift) & 255], 1u);
        if ((k2 & abovemask) == prefix) atomicAdd(&bins[(k2 >> shift) & 255], 1u);
        if ((k3 & abovemask) == prefix) atomicAdd(&bins[(k3 >> shift) & 255], 1u);
        __syncthreads();
        uint32_t s = 0, binv = 0;
        if (t < 256) {
            int jbin = 255 - t;                    // scan bins from the top
            binv = bins[jbin];
            s = binv;
            #pragma unroll
            for (int off = 1; off < 64; off <<= 1) {
                uint32_t u = __shfl_up(s, off);
                if (lane >= off) s += u;
            }
            if (lane == 63) wred[wid] = s;
        }
        __syncthreads();
        if (t < 256) {
            int jbin = 255 - t;
            uint32_t add = 0;
            for (int w = 0; w < wid; ++w) add += wred[w];
            uint32_t sfx_incl = s + add;           // suffix sum over bins >= jbin
            uint32_t sfx_excl = sfx_incl - binv;   // suffix sum over bins >  jbin
            if (sfx_incl >= krem && sfx_excl < krem) {
                sh_bcast[0] = prefix | ((uint32_t)jbin << shift);
                sh_bcast[1] = krem - sfx_excl;
            }
        }
        __syncthreads();
        prefix = sh_bcast[0];
        krem   = sh_bcast[1];
        __syncthreads();
    }

    const uint32_t T    = prefix;                  // k-th largest key
    const uint32_t need = krem;                    // ties to include, lowest index first

    uint32_t e0 = (k0 == T), e1 = (k1 == T), e2 = (k2 == T), e3 = (k3 == T);
    uint32_t c  = e0 + e1 + e2 + e3;

    // exclusive prefix over 1024 threads (thread order == pixel order)
    uint32_t sc = c;
    #pragma unroll
    for (int off = 1; off < 64; off <<= 1) {
        uint32_t u = __shfl_up(sc, off);
        if (lane >= off) sc += u;
    }
    if (lane == 63) wred[wid] = sc;
    __syncthreads();
    uint32_t add = 0;
    for (int w = 0; w < wid; ++w) add += wred[w];
    uint32_t run = (sc - c) + add;                 // ties at lower pixel index

    float4 m;
    m.x = ((k0 > T) || (e0 && run < need)) ? 0.0f : 1.0f; run += e0;
    m.y = ((k1 > T) || (e1 && run < need)) ? 0.0f : 1.0f; run += e1;
    m.z = ((k2 > T) || (e2 && run < need)) ? 0.0f : 1.0f; run += e2;
    m.w = ((k3 > T) || (e3 && run < need)) ? 0.0f : 1.0f; run += e3;
    ((float4*)(mask + (size_t)b * HW_))[t] = m;
}

// Kernel C: out = f * mask (broadcast over channels), float4-vectorized.
__global__ void ps_apply_kernel(const float4* __restrict__ f4,
                                const float4* __restrict__ mask4,
                                float4* __restrict__ out4) {
    size_t i = (size_t)blockIdx.x * blockDim.x + threadIdx.x;  // over 8388608 float4s
    float4 v = f4[i];
    size_t b  = i >> 18;           // (C_*HW_/4) = 262144 float4 per batch
    size_t p4 = i & 1023;          // HW_/4 - 1
    float4 m = mask4[(b << 10) + p4];
    v.x *= m.x; v.y *= m.y; v.z *= m.z; v.w *= m.w;
    out4[i] = v;
}

extern "C" void kernel_launch(void* const* d_in, const int* in_sizes, int n_in,
                              void* d_out, int out_size, void* d_ws, size_t ws_size,
                              hipStream_t stream) {
    const float* f = (const float*)d_in[0];
    float* out = (float*)d_out;

    float* sums = (float*)d_ws;                        // 32*4096 floats = 512 KiB
    float* mask = sums + (size_t)B_ * HW_;             // 32*4096 floats = 512 KiB

    ps_sum_kernel<<<dim3(512), dim3(64), 0, stream>>>((const float4*)f, (float4*)sums);
    ps_select_kernel<<<dim3(B_), dim3(1024), 0, stream>>>(sums, mask);

    size_t total4 = (size_t)B_ * C_ * HW_ / 4;         // 8388608
    ps_apply_kernel<<<dim3((unsigned)(total4 / 256)), dim3(256), 0, stream>>>(
        (const float4*)f, (const float4*)mask, (float4*)out);
}